// Round 5
// baseline (90.948 us; speedup 1.0000x reference)
//
#include <hip/hip_runtime.h>
#include <stdint.h>

typedef __bf16 bf16x8 __attribute__((ext_vector_type(8)));
typedef float f32x4 __attribute__((ext_vector_type(4)));

#define N_ROWS 4096
#define KD 128
#define BM 64
#define BN 64
#define NCHUNK 16
#define CHUNK 256          // cols per block
#define JT (CHUNK / BN)    // 4 j-subtiles per block
#define NBLOCKS (64 * NCHUNK)

// Order-preserving float<->uint32 map: umin/umax on keys == fmin/fmax on floats.
__device__ __forceinline__ unsigned f2key(float f) {
    unsigned b = __float_as_uint(f);
    return (b & 0x80000000u) ? ~b : (b | 0x80000000u);
}
__device__ __forceinline__ float key2f(unsigned k) {
    unsigned b = (k & 0x80000000u) ? (k ^ 0x80000000u) : ~k;
    return __uint_as_float(b);
}

__device__ __forceinline__ unsigned short f32_to_bf16_rne(float f) {
    union { float f; uint32_t u; } v; v.f = f;
    uint32_t u = v.u;
    return (unsigned short)((u + 0x7FFFu + ((u >> 16) & 1u)) >> 16);
}

// XOR-swizzled LDS tile index: uint4 unit (8 bf16) for (row, kblock c) lives at
// row*16 + (c ^ (row & 15)). Coalesced-order writes AND fragment b128 reads
// each cover all 8 bank groups per 8-lane phase -> conflict-free both ways.
__device__ __forceinline__ int swz(int row, int c) { return row * 16 + (c ^ (row & 15)); }
__device__ __forceinline__ int swzL(int L) { return (L & ~15) | ((L & 15) ^ ((L >> 4) & 15)); }

// One wave per row: L2-normalize, bf16 (RNE), pack 2/lane. Also inits the
// per-row min/max key slots and the ticket.
__global__ __launch_bounds__(256) void normalize_kernel(const float* __restrict__ E,
                                                        unsigned short* __restrict__ out,
                                                        unsigned* __restrict__ minkey,
                                                        unsigned* __restrict__ maxkey,
                                                        unsigned* __restrict__ ticket) {
    const int wave = threadIdx.x >> 6;
    const int lane = threadIdx.x & 63;
    const int row = blockIdx.x * 4 + wave;
    if (lane == 0) {
        minkey[row] = f2key(2.0f);    // "no positive" sentinel
        maxkey[row] = f2key(-2.0f);   // "no negative" sentinel
    }
    if (blockIdx.x == 0 && threadIdx.x == 0) *ticket = 0u;
    const float2 v = *(const float2*)&E[row * KD + lane * 2];
    float s = v.x * v.x + v.y * v.y;
#pragma unroll
    for (int m = 1; m < 64; m <<= 1) s += __shfl_xor(s, m, 64);
    float inv = 0.0f;
    if (s > 0.0f) {
        inv = rsqrtf(s);
        inv = inv * (1.5f - 0.5f * s * inv * inv);  // Newton step: ~1e-7 rel err
    }
    const unsigned short a = f32_to_bf16_rne(v.x * inv);
    const unsigned short b = f32_to_bf16_rne(v.y * inv);
    ((uint32_t*)out)[row * (KD / 2) + lane] = ((uint32_t)b << 16) | a;
}

// 1024 blocks = 64 I-tiles x 16 chunks (4/CU). Coalesced staging -> XOR-swizzled
// LDS; register-prefetched B tiles (L2 latency overlaps compute); itile-rotated
// j order (spreads same-line L2 pressure). Epilogue: relaxed device-scope
// atomicMin/Max per row; ticketed last block reduces with batched agent loads.
__global__ __launch_bounds__(256) void gram_kernel(const unsigned short* __restrict__ Ebits,
                                                   const int* __restrict__ labels,
                                                   unsigned* __restrict__ minkey,
                                                   unsigned* __restrict__ maxkey,
                                                   unsigned* __restrict__ ticket,
                                                   float* __restrict__ out) {
    __shared__ uint4 As4[BM * KD / 8];   // 16 KB
    __shared__ uint4 Bs4[BN * KD / 8];   // 16 KB
    __shared__ int ljs[CHUNK];
    __shared__ unsigned s_old;
    __shared__ float ssum[4];
    __shared__ int scnt[4];

    const int tid = threadIdx.x;
    const int itile = blockIdx.x & 63;
    const int chunk = blockIdx.x >> 6;
    const int ibase = itile * BM;
    const int cbase = chunk * CHUNK;
    const bool diagBlock = ((ibase >> 8) == chunk);  // only 64/1024 blocks hold i==j

    // ---- prologue: coalesced global -> regs for A tile and first B tile ----
    uint4 areg[4], breg[4];
    {
        const uint4* asrc = (const uint4*)(Ebits + (size_t)ibase * KD);
        const int rot0 = itile & (JT - 1);
        const uint4* bsrc = (const uint4*)(Ebits + (size_t)(cbase + rot0 * BN) * KD);
#pragma unroll
        for (int it = 0; it < 4; ++it) areg[it] = asrc[it * 256 + tid];
#pragma unroll
        for (int it = 0; it < 4; ++it) breg[it] = bsrc[it * 256 + tid];
        ljs[tid] = labels[cbase + tid];
#pragma unroll
        for (int it = 0; it < 4; ++it) As4[swzL(it * 256 + tid)] = areg[it];
#pragma unroll
        for (int it = 0; it < 4; ++it) Bs4[swzL(it * 256 + tid)] = breg[it];
    }
    __syncthreads();

    const int wave = tid >> 6, lane = tid & 63;
    const int quad = lane >> 4, l15 = lane & 15;
    const int igb = ibase + wave * 16 + quad * 4;  // row base for this lane's accs

    // A fragments: A[m=lane&15][k=quad*8 within 32-step s], held for all p.
    bf16x8 afrag[4];
#pragma unroll
    for (int s = 0; s < 4; ++s) afrag[s] = *(const bf16x8*)&As4[swz(wave * 16 + l15, s * 4 + quad)];

    int li_lab[4];
#pragma unroll
    for (int r = 0; r < 4; ++r) li_lab[r] = labels[igb + r];

    float minpos[4] = {2.0f, 2.0f, 2.0f, 2.0f};
    float maxneg[4] = {-2.0f, -2.0f, -2.0f, -2.0f};

    for (int p = 0; p < JT; ++p) {
        const int rot = (p + itile) & (JT - 1);
        const int jbase = cbase + rot * BN;

        // prefetch next B tile into regs; latency overlaps this tile's MFMAs
        if (p + 1 < JT) {
            const int rotn = (p + 1 + itile) & (JT - 1);
            const uint4* bsrc = (const uint4*)(Ebits + (size_t)(cbase + rotn * BN) * KD);
#pragma unroll
            for (int it = 0; it < 4; ++it) breg[it] = bsrc[it * 256 + tid];
        }

#pragma unroll
        for (int t = 0; t < 4; ++t) {
            f32x4 acc = {0.f, 0.f, 0.f, 0.f};
#pragma unroll
            for (int s = 0; s < 4; ++s) {
                const bf16x8 bfrag = *(const bf16x8*)&Bs4[swz(t * 16 + l15, s * 4 + quad)];
                acc = __builtin_amdgcn_mfma_f32_16x16x32_bf16(afrag[s], bfrag, acc, 0, 0, 0);
            }
            // C/D layout: col = lane&15 (j), row = quad*4 + reg (i)  [m89/m91]
            const int jg = jbase + t * 16 + l15;
            const int lj = ljs[rot * BN + t * 16 + l15];
#pragma unroll
            for (int r = 0; r < 4; ++r) {
                const float d = acc[r];
                const bool same = (lj == li_lab[r]);
                const bool excl = diagBlock && (igb + r == jg);  // diagBlock is wave-uniform
                const float dp = (same && !excl) ? d : 2.0f;
                const float dn = same ? -2.0f : d;
                minpos[r] = fminf(minpos[r], dp);
                maxneg[r] = fmaxf(maxneg[r], dn);
            }
        }

        if (p + 1 < JT) {
            __syncthreads();  // all waves done reading Bs(p)
#pragma unroll
            for (int it = 0; it < 4; ++it) Bs4[swzL(it * 256 + tid)] = breg[it];
            __syncthreads();  // Bs(p+1) published
        }
    }

    // Reduce across the 16 col-lanes of each quad; rows live in (quad,reg).
#pragma unroll
    for (int m = 1; m < 16; m <<= 1) {
#pragma unroll
        for (int r = 0; r < 4; ++r) {
            minpos[r] = fminf(minpos[r], __shfl_xor(minpos[r], m, 64));
            maxneg[r] = fmaxf(maxneg[r], __shfl_xor(maxneg[r], m, 64));
        }
    }
    if (l15 == 0) {
#pragma unroll
        for (int r = 0; r < 4; ++r) {
            atomicMin(&minkey[igb + r], f2key(minpos[r]));  // device-scope, relaxed
            atomicMax(&maxkey[igb + r], f2key(maxneg[r]));
        }
    }

    // syncthreads drains vmcnt(0) -> atomics performed before ticket. No fences.
    __syncthreads();
    if (tid == 0) s_old = atomicAdd(ticket, 1u);
    __syncthreads();
    if (s_old == (unsigned)(NBLOCKS - 1)) {
        float sum = 0.f;
        int cnt = 0;
        unsigned mpk[8], mnk[8];
#pragma unroll
        for (int half = 0; half < 2; ++half) {
            // 8 independent coalesced agent-scope loads in flight per round
#pragma unroll
            for (int u = 0; u < 8; ++u) {
                const int row = tid + 256 * (half * 8 + u);
                mpk[u] = __hip_atomic_load(&minkey[row], __ATOMIC_RELAXED,
                                           __HIP_MEMORY_SCOPE_AGENT);
                mnk[u] = __hip_atomic_load(&maxkey[row], __ATOMIC_RELAXED,
                                           __HIP_MEMORY_SCOPE_AGENT);
            }
#pragma unroll
            for (int u = 0; u < 8; ++u) {
                const float mp = key2f(mpk[u]);
                const float mn = key2f(mnk[u]);
                if (mp < 1.5f && mn > -1.5f) {  // valid: >=1 positive and >=1 negative
                    sum += fmaxf(0.f, mn - mp + 0.3f);
                    cnt += 1;
                }
            }
        }
#pragma unroll
        for (int m = 1; m < 64; m <<= 1) {
            sum += __shfl_xor(sum, m, 64);
            cnt += __shfl_xor(cnt, m, 64);
        }
        if ((tid & 63) == 0) { ssum[tid >> 6] = sum; scnt[tid >> 6] = cnt; }
        __syncthreads();
        if (tid == 0) {
            const float S = ssum[0] + ssum[1] + ssum[2] + ssum[3];
            const int C = scnt[0] + scnt[1] + scnt[2] + scnt[3];
            out[0] = S / (float)(C > 0 ? C : 1);
        }
    }
}

extern "C" void kernel_launch(void* const* d_in, const int* in_sizes, int n_in,
                              void* d_out, int out_size, void* d_ws, size_t ws_size,
                              hipStream_t stream) {
    const float* E = (const float*)d_in[0];
    const int* labels = (const int*)d_in[1];

    unsigned short* ebits = (unsigned short*)d_ws;                          // 1 MiB
    unsigned* minkey = (unsigned*)((char*)d_ws + (size_t)N_ROWS * KD * 2);  // 16 KiB
    unsigned* maxkey = minkey + N_ROWS;                                     // 16 KiB
    unsigned* ticket = maxkey + N_ROWS;                                     // 4 B
    float* out = (float*)d_out;

    normalize_kernel<<<N_ROWS / 4, 256, 0, stream>>>(E, ebits, minkey, maxkey, ticket);
    gram_kernel<<<NBLOCKS, 256, 0, stream>>>(ebits, labels, minkey, maxkey, ticket, out);
}

// Round 6
// 83.505 us; speedup vs baseline: 1.0891x; 1.0891x over previous
//
#include <hip/hip_runtime.h>
#include <stdint.h>

typedef __bf16 bf16x8 __attribute__((ext_vector_type(8)));
typedef float f32x4 __attribute__((ext_vector_type(4)));

#define N_ROWS 4096
#define KD 128
#define BM 64
#define NCHUNK 16
#define CHUNK 256                 // full chunk staged in LDS; no in-loop barriers
#define NBLOCKS (64 * NCHUNK)     // 1024 blocks = 64 I-tiles x 16 chunks

__device__ __forceinline__ unsigned short f32_to_bf16_rne(float f) {
    union { float f; uint32_t u; } v; v.f = f;
    uint32_t u = v.u;
    return (unsigned short)((u + 0x7FFFu + ((u >> 16) & 1u)) >> 16);
}

// XOR-swizzled LDS index for uint4 units: (row, kblock c) -> row*16 + (c ^ (row&15)).
// Coalesced-order writes and fragment b128 reads both cover all 8 bank groups
// per 8-lane phase -> conflict-free both directions.
__device__ __forceinline__ int swz(int row, int c) { return row * 16 + (c ^ (row & 15)); }
__device__ __forceinline__ int swzL(int L) { return (L & ~15) | ((L & 15) ^ ((L >> 4) & 15)); }

// One wave per row: L2-normalize, round to bf16 (RNE), pack 2 elems/lane.
__global__ __launch_bounds__(256) void normalize_kernel(const float* __restrict__ E,
                                                        unsigned short* __restrict__ out) {
    const int wave = threadIdx.x >> 6;
    const int lane = threadIdx.x & 63;
    const int row = blockIdx.x * 4 + wave;
    const float2 v = *(const float2*)&E[row * KD + lane * 2];
    float s = v.x * v.x + v.y * v.y;
#pragma unroll
    for (int m = 1; m < 64; m <<= 1) s += __shfl_xor(s, m, 64);
    float inv = 0.0f;
    if (s > 0.0f) {
        inv = rsqrtf(s);
        inv = inv * (1.5f - 0.5f * s * inv * inv);  // Newton step: ~1e-7 rel err
    }
    const unsigned short a = f32_to_bf16_rne(v.x * inv);
    const unsigned short b = f32_to_bf16_rne(v.y * inv);
    ((uint32_t*)out)[row * (KD / 2) + lane] = ((uint32_t)b << 16) | a;
}

// Block = 64-row I-tile x 256-col chunk. Whole B-chunk (64 KB) staged to
// swizzled LDS ONCE; A-fragments gathered directly from global (no A LDS).
// Exactly one __syncthreads in the kernel -> no per-jt barrier drains.
// 65 KB LDS -> 2 blocks/CU; co-resident block hides the single staging drain.
__global__ __launch_bounds__(256, 2) void gram_kernel(const unsigned short* __restrict__ Ebits,
                                                      const int* __restrict__ labels,
                                                      float2* __restrict__ partials) {
    __shared__ uint4 Bs4[CHUNK * (KD / 8)];  // 64 KB
    __shared__ int ljs[CHUNK];               // 1 KB

    const int tid = threadIdx.x;
    const int itile = blockIdx.x & 63;
    const int chunk = blockIdx.x >> 6;
    const int ibase = itile * BM;
    const int cbase = chunk * CHUNK;

    const int wave = tid >> 6, lane = tid & 63;
    const int quad = lane >> 4, l15 = lane & 15;
    const int igb = ibase + wave * 16 + quad * 4;  // row base for this lane's accs

    // ---- stage: 16 coalesced uint4 loads/thread (whole 256-row chunk) ----
    uint4 breg[16];
    {
        const uint4* bsrc = (const uint4*)(Ebits + (size_t)cbase * KD);
#pragma unroll
        for (int it = 0; it < 16; ++it) breg[it] = bsrc[it * 256 + tid];
    }
    ljs[tid] = labels[cbase + tid];

    // A fragments gathered straight from global (64 x 16B chunks in a 4 KB
    // region per wave; one-time cost). A[m=l15][k = s*32 + quad*8 ..+7].
    bf16x8 afrag[4];
    {
        const uint4* asrc = (const uint4*)Ebits;
        const int arow = ibase + wave * 16 + l15;
#pragma unroll
        for (int s = 0; s < 4; ++s) afrag[s] = *(const bf16x8*)&asrc[arow * 16 + s * 4 + quad];
    }
    int li_lab[4];
#pragma unroll
    for (int r = 0; r < 4; ++r) li_lab[r] = labels[igb + r];

#pragma unroll
    for (int it = 0; it < 16; ++it) Bs4[swzL(it * 256 + tid)] = breg[it];
    __syncthreads();  // the ONLY barrier

    float minpos[4] = {2.0f, 2.0f, 2.0f, 2.0f};   // dots in [-1,1]; 2.0 = "no positive"
    float maxneg[4] = {-2.0f, -2.0f, -2.0f, -2.0f};

    // ---- pure ds_read + MFMA + epilogue stream: 16 j-tiles, no barriers ----
#pragma unroll 4
    for (int t = 0; t < 16; ++t) {
        f32x4 acc = {0.f, 0.f, 0.f, 0.f};
#pragma unroll
        for (int s = 0; s < 4; ++s) {
            const bf16x8 bfrag = *(const bf16x8*)&Bs4[swz(t * 16 + l15, s * 4 + quad)];
            acc = __builtin_amdgcn_mfma_f32_16x16x32_bf16(afrag[s], bfrag, acc, 0, 0, 0);
        }
        // C/D layout: col = lane&15 (j), row = quad*4 + reg (i)  [m89/m91]
        const int jg = cbase + t * 16 + l15;
        const int lj = ljs[t * 16 + l15];  // 16 distinct words, 4-way broadcast: conflict-free
#pragma unroll
        for (int r = 0; r < 4; ++r) {
            const float d = acc[r];
            const bool same = (lj == li_lab[r]);
            const float dp = (same && (igb + r != jg)) ? d : 2.0f;
            const float dn = same ? -2.0f : d;
            minpos[r] = fminf(minpos[r], dp);
            maxneg[r] = fmaxf(maxneg[r], dn);
        }
    }

    // Reduce across the 16 col-lanes of each quad; rows live in (quad,reg).
#pragma unroll
    for (int m = 1; m < 16; m <<= 1) {
#pragma unroll
        for (int r = 0; r < 4; ++r) {
            minpos[r] = fminf(minpos[r], __shfl_xor(minpos[r], m, 64));
            maxneg[r] = fmaxf(maxneg[r], __shfl_xor(maxneg[r], m, 64));
        }
    }
    if (l15 == 0) {
#pragma unroll
        for (int r = 0; r < 4; ++r)
            partials[(igb + r) * NCHUNK + chunk] = make_float2(minpos[r], maxneg[r]);
    }
}

__global__ __launch_bounds__(256) void finalize_kernel(const float2* __restrict__ partials,
                                                       float* __restrict__ out) {
    __shared__ float ssum[4];
    __shared__ int scnt[4];
    float sum = 0.f;
    int cnt = 0;
    for (int row = threadIdx.x; row < N_ROWS; row += 256) {
        float mp = 2.f, mn = -2.f;
        const float4* p4 = (const float4*)&partials[row * NCHUNK];
#pragma unroll
        for (int c = 0; c < NCHUNK / 2; ++c) {
            const float4 v = p4[c];            // {min0,max0,min1,max1}
            mp = fminf(mp, fminf(v.x, v.z));
            mn = fmaxf(mn, fmaxf(v.y, v.w));
        }
        if (mp < 1.5f && mn > -1.5f) {         // valid: >=1 positive and >=1 negative
            sum += fmaxf(0.f, mn - mp + 0.3f); // relu(hp - hn + margin)
            cnt += 1;
        }
    }
#pragma unroll
    for (int m = 1; m < 64; m <<= 1) {
        sum += __shfl_xor(sum, m, 64);
        cnt += __shfl_xor(cnt, m, 64);
    }
    const int wave = threadIdx.x >> 6, lane = threadIdx.x & 63;
    if (lane == 0) { ssum[wave] = sum; scnt[wave] = cnt; }
    __syncthreads();
    if (threadIdx.x == 0) {
        const float S = ssum[0] + ssum[1] + ssum[2] + ssum[3];
        const int C = scnt[0] + scnt[1] + scnt[2] + scnt[3];
        out[0] = S / (float)(C > 0 ? C : 1);
    }
}

extern "C" void kernel_launch(void* const* d_in, const int* in_sizes, int n_in,
                              void* d_out, int out_size, void* d_ws, size_t ws_size,
                              hipStream_t stream) {
    const float* E = (const float*)d_in[0];
    const int* labels = (const int*)d_in[1];

    unsigned short* ebits = (unsigned short*)d_ws;                          // 1 MiB
    float2* partials = (float2*)((char*)d_ws + (size_t)N_ROWS * KD * 2);    // 512 KiB
    float* out = (float*)d_out;

    normalize_kernel<<<N_ROWS / 4, 256, 0, stream>>>(E, ebits);
    gram_kernel<<<NBLOCKS, 256, 0, stream>>>(ebits, labels, partials);
    finalize_kernel<<<1, 256, 0, stream>>>(partials, out);
}

// Round 7
// 74.463 us; speedup vs baseline: 1.2214x; 1.1214x over previous
//
#include <hip/hip_runtime.h>
#include <stdint.h>

typedef __bf16 bf16x8 __attribute__((ext_vector_type(8)));
typedef float f32x4 __attribute__((ext_vector_type(4)));

#define N_ROWS 4096
#define KD 128
#define BM 64
#define BN 64
#define NCHUNK 16
#define CHUNK 256          // cols per block
#define JT (CHUNK / BN)    // 4 j-subtiles per block
#define NBLOCKS (64 * NCHUNK)
#define FIN_BLOCKS 64

__device__ __forceinline__ unsigned short f32_to_bf16_rne(float f) {
    union { float f; uint32_t u; } v; v.f = f;
    uint32_t u = v.u;
    return (unsigned short)((u + 0x7FFFu + ((u >> 16) & 1u)) >> 16);
}

// XOR-swizzled LDS index for uint4 units: (row, kblock c) -> row*16 + (c ^ (row&15)).
// Both coalesced-order ds_write_b128 and fragment ds_read_b128 land <=2 lanes
// per bank group per phase -> conflict-free (2-way is free, m136).
__device__ __forceinline__ int swz(int row, int c) { return row * 16 + (c ^ (row & 15)); }
__device__ __forceinline__ int swzL(int L) { return (L & ~15) | ((L & 15) ^ ((L >> 4) & 15)); }

// One wave per row: L2-normalize, round to bf16 (RNE), pack 2 elems/lane.
// Thread (0,0) also zeroes finalize's accumulators + ticket.
__global__ __launch_bounds__(256) void normalize_kernel(const float* __restrict__ E,
                                                        unsigned short* __restrict__ out,
                                                        float* __restrict__ gsum,
                                                        unsigned* __restrict__ gcnt,
                                                        unsigned* __restrict__ ticket) {
    if (blockIdx.x == 0 && threadIdx.x == 0) {
        *gsum = 0.0f; *gcnt = 0u; *ticket = 0u;
    }
    const int wave = threadIdx.x >> 6;
    const int lane = threadIdx.x & 63;
    const int row = blockIdx.x * 4 + wave;
    const float2 v = *(const float2*)&E[row * KD + lane * 2];
    float s = v.x * v.x + v.y * v.y;
#pragma unroll
    for (int m = 1; m < 64; m <<= 1) s += __shfl_xor(s, m, 64);
    float inv = 0.0f;
    if (s > 0.0f) {
        inv = rsqrtf(s);
        inv = inv * (1.5f - 0.5f * s * inv * inv);  // Newton step: ~1e-7 rel err
    }
    const unsigned short a = f32_to_bf16_rne(v.x * inv);
    const unsigned short b = f32_to_bf16_rne(v.y * inv);
    ((uint32_t*)out)[row * (KD / 2) + lane] = ((uint32_t)b << 16) | a;
}

// R2-proven shape: 1024 blocks = 64 I-tiles x 16 chunks (4 blocks/CU), per-jt
// B staging with 2 barriers, now with XOR-swizzled LDS (0 bank conflicts).
__global__ __launch_bounds__(256) void gram_kernel(const unsigned short* __restrict__ Ebits,
                                                   const int* __restrict__ labels,
                                                   float2* __restrict__ partials) {
    __shared__ uint4 As4[BM * KD / 8];   // 16 KB
    __shared__ uint4 Bs4[BN * KD / 8];   // 16 KB
    __shared__ int ljs[CHUNK];           // 1 KB

    const int tid = threadIdx.x;
    const int itile = blockIdx.x & 63;
    const int chunk = blockIdx.x >> 6;
    const int ibase = itile * BM;
    const int cbase = chunk * CHUNK;

    // Stage A-tile (coalesced uint4 -> swizzled LDS) + chunk labels.
    {
        const uint4* src = (const uint4*)(Ebits + (size_t)ibase * KD);
#pragma unroll
        for (int it = 0; it < 4; ++it) {
            const int L = it * 256 + tid;
            As4[swzL(L)] = src[L];
        }
        ljs[tid] = labels[cbase + tid];
    }
    __syncthreads();

    const int wave = tid >> 6, lane = tid & 63;
    const int quad = lane >> 4, l15 = lane & 15;
    const int igb = ibase + wave * 16 + quad * 4;  // row base for this lane's accs

    // A fragments: A[m=lane&15][k = s*32 + quad*8 ..+7], held for the whole chunk.
    bf16x8 afrag[4];
#pragma unroll
    for (int s = 0; s < 4; ++s)
        afrag[s] = *(const bf16x8*)&As4[swz(wave * 16 + l15, s * 4 + quad)];

    int li_lab[4];
#pragma unroll
    for (int r = 0; r < 4; ++r) li_lab[r] = labels[igb + r];

    float minpos[4] = {2.0f, 2.0f, 2.0f, 2.0f};   // dots in [-1,1]; 2.0 = "no positive"
    float maxneg[4] = {-2.0f, -2.0f, -2.0f, -2.0f};

    for (int jt = 0; jt < JT; ++jt) {
        const int jbase = cbase + jt * BN;
        __syncthreads();  // prev iter's Bs reads done
        {
            const uint4* src = (const uint4*)(Ebits + (size_t)jbase * KD);
#pragma unroll
            for (int it = 0; it < 4; ++it) {
                const int L = it * 256 + tid;
                Bs4[swzL(L)] = src[L];
            }
        }
        __syncthreads();

#pragma unroll
        for (int t = 0; t < 4; ++t) {
            f32x4 acc = {0.f, 0.f, 0.f, 0.f};
#pragma unroll
            for (int s = 0; s < 4; ++s) {
                const bf16x8 bfrag = *(const bf16x8*)&Bs4[swz(t * 16 + l15, s * 4 + quad)];
                acc = __builtin_amdgcn_mfma_f32_16x16x32_bf16(afrag[s], bfrag, acc, 0, 0, 0);
            }
            // C/D layout: col = lane&15 (j), row = quad*4 + reg (i)  [m89/m91]
            const int jg = jbase + t * 16 + l15;
            const int lj = ljs[jt * BN + t * 16 + l15];
#pragma unroll
            for (int r = 0; r < 4; ++r) {
                const float d = acc[r];
                const bool same = (lj == li_lab[r]);
                const float dp = (same && (igb + r != jg)) ? d : 2.0f;
                const float dn = same ? -2.0f : d;
                minpos[r] = fminf(minpos[r], dp);
                maxneg[r] = fmaxf(maxneg[r], dn);
            }
        }
    }

    // Reduce across the 16 col-lanes of each quad; rows live in (quad,reg).
#pragma unroll
    for (int m = 1; m < 16; m <<= 1) {
#pragma unroll
        for (int r = 0; r < 4; ++r) {
            minpos[r] = fminf(minpos[r], __shfl_xor(minpos[r], m, 64));
            maxneg[r] = fmaxf(maxneg[r], __shfl_xor(maxneg[r], m, 64));
        }
    }
    if (l15 == 0) {
#pragma unroll
        for (int r = 0; r < 4; ++r)
            partials[(igb + r) * NCHUNK + chunk] = make_float2(minpos[r], maxneg[r]);
    }
}

// 64 blocks x 64 rows: coalesced 4-thread/row reduce of partials, then 2
// atomicAdds + ticket; last block writes the scalar loss. (R4 lesson: the
// atomic protocol is sound; only its *volume* was the problem. 130 atomics
// total here.)
__global__ __launch_bounds__(256) void finalize_kernel(const float2* __restrict__ partials,
                                                       float* __restrict__ gsum,
                                                       unsigned* __restrict__ gcnt,
                                                       unsigned* __restrict__ ticket,
                                                       float* __restrict__ out) {
    __shared__ float ssum[4];
    __shared__ int scnt[4];
    __shared__ unsigned s_old;

    const int tid = threadIdx.x;
    const int sub = tid & 3;                  // quarter of the 16 chunks
    const int row = blockIdx.x * 64 + (tid >> 2);

    const float4* p4 = (const float4*)&partials[row * NCHUNK];  // 8 float4 / row
    const float4 a = p4[sub * 2];
    const float4 b = p4[sub * 2 + 1];
    float mp = fminf(fminf(a.x, a.z), fminf(b.x, b.z));
    float mn = fmaxf(fmaxf(a.y, a.w), fmaxf(b.y, b.w));
    // combine the 4 sub-lanes of each row
    mp = fminf(mp, __shfl_xor(mp, 1, 64)); mp = fminf(mp, __shfl_xor(mp, 2, 64));
    mn = fmaxf(mn, __shfl_xor(mn, 1, 64)); mn = fmaxf(mn, __shfl_xor(mn, 2, 64));

    float sum = 0.f; int cnt = 0;
    if (sub == 0 && mp < 1.5f && mn > -1.5f) {   // valid: >=1 pos and >=1 neg
        sum = fmaxf(0.f, mn - mp + 0.3f);        // relu(hp - hn + margin)
        cnt = 1;
    }
#pragma unroll
    for (int m = 1; m < 64; m <<= 1) {
        sum += __shfl_xor(sum, m, 64);
        cnt += __shfl_xor(cnt, m, 64);
    }
    const int wave = tid >> 6, lane = tid & 63;
    if (lane == 0) { ssum[wave] = sum; scnt[wave] = cnt; }
    __syncthreads();
    if (tid == 0) {
        atomicAdd(gsum, ssum[0] + ssum[1] + ssum[2] + ssum[3]);
        atomicAdd(gcnt, (unsigned)(scnt[0] + scnt[1] + scnt[2] + scnt[3]));
    }
    __syncthreads();                 // drain the adds (vmcnt) before ticket
    if (tid == 0) s_old = atomicAdd(ticket, 1u);
    __syncthreads();
    if (s_old == (unsigned)(FIN_BLOCKS - 1) && tid == 0) {
        const float S = __hip_atomic_load(gsum, __ATOMIC_RELAXED, __HIP_MEMORY_SCOPE_AGENT);
        const unsigned C = __hip_atomic_load(gcnt, __ATOMIC_RELAXED, __HIP_MEMORY_SCOPE_AGENT);
        out[0] = S / (float)(C > 0u ? C : 1u);
    }
}

extern "C" void kernel_launch(void* const* d_in, const int* in_sizes, int n_in,
                              void* d_out, int out_size, void* d_ws, size_t ws_size,
                              hipStream_t stream) {
    const float* E = (const float*)d_in[0];
    const int* labels = (const int*)d_in[1];

    unsigned short* ebits = (unsigned short*)d_ws;                          // 1 MiB
    float2* partials = (float2*)((char*)d_ws + (size_t)N_ROWS * KD * 2);    // 512 KiB
    float* gsum = (float*)(partials + N_ROWS * NCHUNK);
    unsigned* gcnt = (unsigned*)(gsum + 1);
    unsigned* ticket = gcnt + 1;
    float* out = (float*)d_out;

    normalize_kernel<<<N_ROWS / 4, 256, 0, stream>>>(E, ebits, gsum, gcnt, ticket);
    gram_kernel<<<NBLOCKS, 256, 0, stream>>>(ebits, labels, partials);
    finalize_kernel<<<FIN_BLOCKS, 256, 0, stream>>>(partials, gsum, gcnt, ticket, out);
}